// Round 1
// baseline (697.571 us; speedup 1.0000x reference)
//
#include <hip/hip_runtime.h>
#include <hip/hip_bf16.h>

#define NEG_ (-1e10f)

typedef short bf16x8 __attribute__((ext_vector_type(8)));   // 8 bf16 in 4 VGPRs
typedef float f32x4 __attribute__((ext_vector_type(4)));

__device__ __forceinline__ unsigned int pack_bf16x2(float a, float b) {
    __hip_bfloat162 h = __float22bfloat162_rn(make_float2(a, b));
    union { __hip_bfloat162 h2; unsigned int u; } cv;
    cv.h2 = h;
    return cv.u;
}

// ---------------- kernel 1: hb[b][k] = hidden[b,:] . w_h[k,:] + attn_b[k] ----------------
__global__ __launch_bounds__(256) void hproj_kernel(const float* __restrict__ hidden,
                                                    const float* __restrict__ attn_w,
                                                    const float* __restrict__ attn_b,
                                                    float* __restrict__ hb) {
    __shared__ float row[1024];
    const int k = blockIdx.x;          // 0..1023
    const int t = threadIdx.x;
    // stage w_h row k (first half of attn_w row; row stride 2048)
    *reinterpret_cast<float4*>(&row[t * 4]) =
        *reinterpret_cast<const float4*>(&attn_w[(size_t)k * 2048 + t * 4]);
    __syncthreads();
    const int w = t >> 6, l = t & 63;
    const float bias = attn_b[k];
    for (int bi = 0; bi < 8; ++bi) {
        const int b = w * 8 + bi;
        const float* hrow = hidden + b * 1024;
        float p = 0.f;
#pragma unroll
        for (int i = 0; i < 16; ++i) p += hrow[l + 64 * i] * row[l + 64 * i];
#pragma unroll
        for (int off = 32; off > 0; off >>= 1) p += __shfl_xor(p, off);
        if (l == 0) hb[b * 1024 + k] = p + bias;
    }
}

// ---------------- kernel 2: fused energy GEMM + tanh + v_w row-reduce ----------------
// logits[m] += sum_n v_w[n] * tanh( enc[m,:] . w_e[n,:] + hb[b(m),n] )
// M=65536, N=1024, inner=1024.  BM=BN=128, BK=64, 4 waves (2x2), bf16 MFMA 16x16x32.
__global__ __launch_bounds__(256, 2) void energy_gemm_kernel(const float* __restrict__ enc,
                                                             const float* __restrict__ attn_w,
                                                             const float* __restrict__ hb,
                                                             const float* __restrict__ v_w,
                                                             float* __restrict__ logits) {
    __shared__ unsigned int As[128 * 36];   // 128 rows x 72 bf16 (64 + 8 pad) = 144B stride
    __shared__ unsigned int Bs[128 * 36];

    const int t    = threadIdx.x;
    const int lane = t & 63;
    const int wid  = t >> 6;
    const int wm   = wid >> 1, wn = wid & 1;

    // XCD-chunked swizzle: XCD x gets logical ids [x*512, (x+1)*512), ni fastest
    const int bid     = blockIdx.x;
    const int logical = (bid & 7) * 512 + (bid >> 3);
    const int mi = logical >> 3, ni = logical & 7;
    const size_t m0 = (size_t)mi * 128;
    const int n0 = ni * 128;
    const int b  = mi >> 4;                 // 16 m-tiles per batch

    f32x4 acc[4][4];
#pragma unroll
    for (int i = 0; i < 4; ++i)
#pragma unroll
        for (int j = 0; j < 4; ++j) acc[i][j] = f32x4{0.f, 0.f, 0.f, 0.f};

    const int rA = t >> 3;                  // 0..31
    const int c8 = (t & 7) * 8;             // col base (floats)
    const float* Agb = enc + m0 * 1024;
    const float* Bgb = attn_w + (size_t)n0 * 2048 + 1024;   // w_e = attn_w[:,1024:]

    for (int kt = 0; kt < 16; ++kt) {
        const int e0 = kt * 64;
        __syncthreads();
#pragma unroll
        for (int i = 0; i < 4; ++i) {
            const int r = rA + i * 32;
            const float* srcA = Agb + (size_t)r * 1024 + e0 + c8;
            float4 a0 = *reinterpret_cast<const float4*>(srcA);
            float4 a1 = *reinterpret_cast<const float4*>(srcA + 4);
            uint4 ua = {pack_bf16x2(a0.x, a0.y), pack_bf16x2(a0.z, a0.w),
                        pack_bf16x2(a1.x, a1.y), pack_bf16x2(a1.z, a1.w)};
            *reinterpret_cast<uint4*>(&As[r * 36 + (t & 7) * 4]) = ua;

            const float* srcB = Bgb + (size_t)r * 2048 + e0 + c8;
            float4 b0 = *reinterpret_cast<const float4*>(srcB);
            float4 b1 = *reinterpret_cast<const float4*>(srcB + 4);
            uint4 ub = {pack_bf16x2(b0.x, b0.y), pack_bf16x2(b0.z, b0.w),
                        pack_bf16x2(b1.x, b1.y), pack_bf16x2(b1.z, b1.w)};
            *reinterpret_cast<uint4*>(&Bs[r * 36 + (t & 7) * 4]) = ub;
        }
        __syncthreads();
#pragma unroll
        for (int ks = 0; ks < 2; ++ks) {
            bf16x8 af[4], bf[4];
            const int colu = ks * 16 + (lane >> 4) * 4;    // uint offset within row
#pragma unroll
            for (int fm = 0; fm < 4; ++fm)
                af[fm] = *reinterpret_cast<const bf16x8*>(
                    &As[(wm * 64 + fm * 16 + (lane & 15)) * 36 + colu]);
#pragma unroll
            for (int fn = 0; fn < 4; ++fn)
                bf[fn] = *reinterpret_cast<const bf16x8*>(
                    &Bs[(wn * 64 + fn * 16 + (lane & 15)) * 36 + colu]);
#pragma unroll
            for (int fm = 0; fm < 4; ++fm)
#pragma unroll
                for (int fn = 0; fn < 4; ++fn)
                    acc[fm][fn] = __builtin_amdgcn_mfma_f32_16x16x32_bf16(
                        af[fm], bf[fn], acc[fm][fn], 0, 0, 0);
        }
    }

    // epilogue: tanh + v_w weighting + row reduction
    const int cl = lane & 15, rg = lane >> 4;
    float rs[4][4];
#pragma unroll
    for (int i = 0; i < 4; ++i)
#pragma unroll
        for (int j = 0; j < 4; ++j) rs[i][j] = 0.f;

#pragma unroll
    for (int fn = 0; fn < 4; ++fn) {
        const int n = n0 + wn * 64 + fn * 16 + cl;
        const float hbv = hb[b * 1024 + n];
        const float vwv = v_w[n];
#pragma unroll
        for (int fm = 0; fm < 4; ++fm) {
#pragma unroll
            for (int r = 0; r < 4; ++r) {
                float x  = acc[fm][fn][r] + hbv;
                float x2 = fminf(fmaxf(2.f * x, -80.f), 80.f);
                float ex = __expf(x2);
                float th = 1.f - 2.f / (ex + 1.f);   // tanh(x)
                rs[fm][r] += th * vwv;
            }
        }
    }
#pragma unroll
    for (int fm = 0; fm < 4; ++fm) {
#pragma unroll
        for (int r = 0; r < 4; ++r) {
            float v = rs[fm][r];
            v += __shfl_xor(v, 1);
            v += __shfl_xor(v, 2);
            v += __shfl_xor(v, 4);
            v += __shfl_xor(v, 8);
            if (cl == 0)
                atomicAdd(&logits[m0 + wm * 64 + fm * 16 + rg * 4 + r], v);
        }
    }
}

// ---------------- kernel 3: masked softmax over S=2048 per batch row ----------------
__global__ __launch_bounds__(256) void softmax_kernel(const float* __restrict__ logits,
                                                      const int* __restrict__ mask,
                                                      float* __restrict__ wout) {
    const int b = blockIdx.x, t = threadIdx.x;
    __shared__ float red[4];
    float v[8];
    float m = -3.4e38f;
#pragma unroll
    for (int i = 0; i < 8; ++i) {
        const int s = t + i * 256;
        float x = logits[b * 2048 + s];
        if (mask[b * 2048 + s] == 0) x = NEG_;
        v[i] = x;
        m = fmaxf(m, x);
    }
#pragma unroll
    for (int off = 32; off > 0; off >>= 1) m = fmaxf(m, __shfl_xor(m, off));
    if ((t & 63) == 0) red[t >> 6] = m;
    __syncthreads();
    m = fmaxf(fmaxf(red[0], red[1]), fmaxf(red[2], red[3]));
    __syncthreads();
    float sum = 0.f;
#pragma unroll
    for (int i = 0; i < 8; ++i) {
        v[i] = __expf(v[i] - m);
        sum += v[i];
    }
#pragma unroll
    for (int off = 32; off > 0; off >>= 1) sum += __shfl_xor(sum, off);
    if ((t & 63) == 0) red[t >> 6] = sum;
    __syncthreads();
    sum = red[0] + red[1] + red[2] + red[3];
    const float inv = 1.f / sum;
#pragma unroll
    for (int i = 0; i < 8; ++i) wout[b * 2048 + t + i * 256] = v[i] * inv;
}

// ---------------- kernel 4: context partial sums over s-splits ----------------
__global__ __launch_bounds__(256) void ctx_partial_kernel(const float* __restrict__ enc,
                                                          const float* __restrict__ wts,
                                                          float* __restrict__ part) {
    const int b  = blockIdx.x >> 4;
    const int sp = blockIdx.x & 15;
    const int t  = threadIdx.x;
    const float* wrow = wts + b * 2048 + sp * 128;
    const float* erow = enc + ((size_t)b * 2048 + sp * 128) * 1024 + t * 4;
    float4 acc = {0.f, 0.f, 0.f, 0.f};
#pragma unroll 4
    for (int s = 0; s < 128; ++s) {
        const float w = wrow[s];
        float4 e = *reinterpret_cast<const float4*>(erow + (size_t)s * 1024);
        acc.x += w * e.x; acc.y += w * e.y; acc.z += w * e.z; acc.w += w * e.w;
    }
    *reinterpret_cast<float4*>(&part[(size_t)blockIdx.x * 1024 + t * 4]) = acc;
}

// ---------------- kernel 5: reduce partials into context ----------------
__global__ __launch_bounds__(256) void ctx_reduce_kernel(const float* __restrict__ part,
                                                         float* __restrict__ ctx) {
    const int idx = blockIdx.x * 256 + threadIdx.x;   // 0..32767
    const int b = idx >> 10, e = idx & 1023;
    float s = 0.f;
#pragma unroll
    for (int sp = 0; sp < 16; ++sp) s += part[(size_t)(b * 16 + sp) * 1024 + e];
    ctx[idx] = s;
}

extern "C" void kernel_launch(void* const* d_in, const int* in_sizes, int n_in,
                              void* d_out, int out_size, void* d_ws, size_t ws_size,
                              hipStream_t stream) {
    const float* hidden = (const float*)d_in[0];
    const float* enc    = (const float*)d_in[1];
    const int*   mask   = (const int*)d_in[2];
    const float* attn_w = (const float*)d_in[3];
    const float* attn_b = (const float*)d_in[4];
    const float* v_w    = (const float*)d_in[5];

    float* out    = (float*)d_out;
    float* ctx    = out;                 // 32*1024
    float* wts    = out + 32 * 1024;     // 32*2048
    float* hb     = (float*)d_ws;        // 32*1024
    float* logits = hb + 32 * 1024;      // 32*2048
    float* part   = logits + 32 * 2048;  // 512*1024

    hipMemsetAsync(logits, 0, 32 * 2048 * sizeof(float), stream);
    hproj_kernel<<<1024, 256, 0, stream>>>(hidden, attn_w, attn_b, hb);
    energy_gemm_kernel<<<4096, 256, 0, stream>>>(enc, attn_w, hb, v_w, logits);
    softmax_kernel<<<32, 256, 0, stream>>>(logits, mask, wts);
    ctx_partial_kernel<<<512, 256, 0, stream>>>(enc, wts, part);
    ctx_reduce_kernel<<<128, 256, 0, stream>>>(part, ctx);
}

// Round 2
// 666.867 us; speedup vs baseline: 1.0460x; 1.0460x over previous
//
#include <hip/hip_runtime.h>
#include <hip/hip_bf16.h>

#define NEG_ (-1e10f)

typedef short bf16x8 __attribute__((ext_vector_type(8)));   // 8 bf16 in 4 VGPRs
typedef float f32x4 __attribute__((ext_vector_type(4)));

__device__ __forceinline__ unsigned int pack_bf16x2(float a, float b) {
    __hip_bfloat162 h = __float22bfloat162_rn(make_float2(a, b));
    union { __hip_bfloat162 h2; unsigned int u; } cv;
    cv.h2 = h;
    return cv.u;
}

__device__ __forceinline__ void gload_lds16(const void* g, void* lds) {
    __builtin_amdgcn_global_load_lds(
        (const __attribute__((address_space(1))) unsigned int*)g,
        (__attribute__((address_space(3))) unsigned int*)lds,
        16, 0, 0);
}

// ---------------- kernel 0a: convert enc f32 -> bf16 (67.1M elems) ----------------
__global__ __launch_bounds__(256) void cvt_enc_kernel(const float* __restrict__ enc,
                                                      unsigned int* __restrict__ encbf /*as uint4*/) {
    const int tid = blockIdx.x * 256 + threadIdx.x;   // 0..1048575
#pragma unroll
    for (int i = 0; i < 8; ++i) {
        const size_t c = (size_t)tid + (size_t)i * 1048576;   // chunk of 8 floats
        const float4 a0 = *reinterpret_cast<const float4*>(enc + c * 8);
        const float4 a1 = *reinterpret_cast<const float4*>(enc + c * 8 + 4);
        uint4 u = {pack_bf16x2(a0.x, a0.y), pack_bf16x2(a0.z, a0.w),
                   pack_bf16x2(a1.x, a1.y), pack_bf16x2(a1.z, a1.w)};
        *reinterpret_cast<uint4*>(encbf + c * 4) = u;
    }
}

// ---------------- kernel 0b: convert w_e (attn_w[:,1024:]) f32 -> bf16 ----------------
__global__ __launch_bounds__(256) void cvt_w_kernel(const float* __restrict__ attn_w,
                                                    unsigned int* __restrict__ wbf) {
    const int idx = blockIdx.x * 256 + threadIdx.x;   // 0..131071
    const int row = idx >> 7;
    const int c   = (idx & 127) * 8;
    const float* src = attn_w + (size_t)row * 2048 + 1024 + c;
    const float4 a0 = *reinterpret_cast<const float4*>(src);
    const float4 a1 = *reinterpret_cast<const float4*>(src + 4);
    uint4 u = {pack_bf16x2(a0.x, a0.y), pack_bf16x2(a0.z, a0.w),
               pack_bf16x2(a1.x, a1.y), pack_bf16x2(a1.z, a1.w)};
    *reinterpret_cast<uint4*>(wbf + (size_t)row * 512 + c / 2) = u;
}

// ---------------- kernel 1: hb[b][k] = hidden[b,:] . w_h[k,:] + attn_b[k] ----------------
__global__ __launch_bounds__(256) void hproj_kernel(const float* __restrict__ hidden,
                                                    const float* __restrict__ attn_w,
                                                    const float* __restrict__ attn_b,
                                                    float* __restrict__ hb) {
    __shared__ float row[1024];
    const int k = blockIdx.x;
    const int t = threadIdx.x;
    *reinterpret_cast<float4*>(&row[t * 4]) =
        *reinterpret_cast<const float4*>(&attn_w[(size_t)k * 2048 + t * 4]);
    __syncthreads();
    const int w = t >> 6, l = t & 63;
    const float bias = attn_b[k];
    for (int bi = 0; bi < 8; ++bi) {
        const int b = w * 8 + bi;
        const float* hrow = hidden + b * 1024;
        float p = 0.f;
#pragma unroll
        for (int i = 0; i < 16; ++i) p += hrow[l + 64 * i] * row[l + 64 * i];
#pragma unroll
        for (int off = 32; off > 0; off >>= 1) p += __shfl_xor(p, off);
        if (l == 0) hb[b * 1024 + k] = p + bias;
    }
}

// ---------------- kernel 2: bf16 energy GEMM (m97 structure) + tanh + v_w reduce ----------------
// logits[m] += sum_n v_w[n] * tanh( A[m,:] . B[n,:] + hb[b(m),n] ),  A=encbf, B=wbf
// M=65536, N=1024, K=1024. BM=BN=128, BK=64, 4 waves (2x2), mfma 16x16x32 bf16.
__global__ __launch_bounds__(256, 3) void energy_gemm_kernel(const __hip_bfloat16* __restrict__ Abf,
                                                             const __hip_bfloat16* __restrict__ Bbf,
                                                             const float* __restrict__ hb,
                                                             const float* __restrict__ v_w,
                                                             float* __restrict__ logits) {
    __shared__ short As[128 * 64];   // linear [row][64] bf16, 128 B/row
    __shared__ short Bs[128 * 64];

    const int t    = threadIdx.x;
    const int lane = t & 63;
    const int w    = t >> 6;
    const int wm   = w >> 1, wn = w & 1;

    // XCD-chunked swizzle (4096 % 8 == 0 -> bijective), ni fastest within chunk
    const int logical = (blockIdx.x & 7) * 512 + (blockIdx.x >> 3);
    const int mi = logical >> 3, ni = logical & 7;
    const size_t m0 = (size_t)mi * 128;
    const int n0 = ni * 128;
    const int b  = mi >> 4;

    f32x4 acc[4][4];
#pragma unroll
    for (int i = 0; i < 4; ++i)
#pragma unroll
        for (int j = 0; j < 4; ++j) acc[i][j] = f32x4{0.f, 0.f, 0.f, 0.f};

    // staging source: wave w covers rows [w*32, w*32+32), lane l -> row +(l>>3), colbyte (l&7)*16
    const char* Asrc = (const char*)Abf + ((m0 + w * 32 + (lane >> 3)) * 1024 + 0) * 2 + (lane & 7) * 16;
    const char* Bsrc = (const char*)Bbf + (((size_t)n0 + w * 32 + (lane >> 3)) * 1024) * 2 + (lane & 7) * 16;
    char* AsBase = (char*)As + w * 4096;
    char* BsBase = (char*)Bs + w * 4096;

    for (int kt = 0; kt < 16; ++kt) {
        const size_t ko = (size_t)kt * 128;   // byte offset along K
        __syncthreads();
#pragma unroll
        for (int i = 0; i < 4; ++i) {
            gload_lds16(Asrc + (size_t)i * 8 * 2048 + ko, AsBase + i * 1024);
            gload_lds16(Bsrc + (size_t)i * 8 * 2048 + ko, BsBase + i * 1024);
        }
        __syncthreads();
#pragma unroll
        for (int ks = 0; ks < 2; ++ks) {
            bf16x8 af[4], bfr[4];
            const int cbyte = ks * 64 + (lane >> 4) * 16;
#pragma unroll
            for (int fm = 0; fm < 4; ++fm)
                af[fm] = *reinterpret_cast<const bf16x8*>(
                    (const char*)As + (wm * 64 + fm * 16 + (lane & 15)) * 128 + cbyte);
#pragma unroll
            for (int fn = 0; fn < 4; ++fn)
                bfr[fn] = *reinterpret_cast<const bf16x8*>(
                    (const char*)Bs + (wn * 64 + fn * 16 + (lane & 15)) * 128 + cbyte);
#pragma unroll
            for (int fm = 0; fm < 4; ++fm)
#pragma unroll
                for (int fn = 0; fn < 4; ++fn)
                    acc[fm][fn] = __builtin_amdgcn_mfma_f32_16x16x32_bf16(
                        af[fm], bfr[fn], acc[fm][fn], 0, 0, 0);
        }
    }

    // epilogue: tanh + v_w weighting + row reduction (validated in R1)
    const int cl = lane & 15, rg = lane >> 4;
    float rs[4][4];
#pragma unroll
    for (int i = 0; i < 4; ++i)
#pragma unroll
        for (int j = 0; j < 4; ++j) rs[i][j] = 0.f;

#pragma unroll
    for (int fn = 0; fn < 4; ++fn) {
        const int n = n0 + wn * 64 + fn * 16 + cl;
        const float hbv = hb[b * 1024 + n];
        const float vwv = v_w[n];
#pragma unroll
        for (int fm = 0; fm < 4; ++fm) {
#pragma unroll
            for (int r = 0; r < 4; ++r) {
                float x  = acc[fm][fn][r] + hbv;
                float x2 = fminf(fmaxf(2.f * x, -80.f), 80.f);
                float ex = __expf(x2);
                float th = 1.f - 2.f / (ex + 1.f);
                rs[fm][r] += th * vwv;
            }
        }
    }
#pragma unroll
    for (int fm = 0; fm < 4; ++fm) {
#pragma unroll
        for (int r = 0; r < 4; ++r) {
            float v = rs[fm][r];
            v += __shfl_xor(v, 1);
            v += __shfl_xor(v, 2);
            v += __shfl_xor(v, 4);
            v += __shfl_xor(v, 8);
            if (cl == 0)
                atomicAdd(&logits[m0 + wm * 64 + fm * 16 + rg * 4 + r], v);
        }
    }
}

// ---------------- kernel 3: masked softmax over S=2048 per batch row ----------------
__global__ __launch_bounds__(256) void softmax_kernel(const float* __restrict__ logits,
                                                      const int* __restrict__ mask,
                                                      float* __restrict__ wout) {
    const int b = blockIdx.x, t = threadIdx.x;
    __shared__ float red[4];
    float v[8];
    float m = -3.4e38f;
#pragma unroll
    for (int i = 0; i < 8; ++i) {
        const int s = t + i * 256;
        float x = logits[b * 2048 + s];
        if (mask[b * 2048 + s] == 0) x = NEG_;
        v[i] = x;
        m = fmaxf(m, x);
    }
#pragma unroll
    for (int off = 32; off > 0; off >>= 1) m = fmaxf(m, __shfl_xor(m, off));
    if ((t & 63) == 0) red[t >> 6] = m;
    __syncthreads();
    m = fmaxf(fmaxf(red[0], red[1]), fmaxf(red[2], red[3]));
    __syncthreads();
    float sum = 0.f;
#pragma unroll
    for (int i = 0; i < 8; ++i) {
        v[i] = __expf(v[i] - m);
        sum += v[i];
    }
#pragma unroll
    for (int off = 32; off > 0; off >>= 1) sum += __shfl_xor(sum, off);
    if ((t & 63) == 0) red[t >> 6] = sum;
    __syncthreads();
    sum = red[0] + red[1] + red[2] + red[3];
    const float inv = 1.f / sum;
#pragma unroll
    for (int i = 0; i < 8; ++i) wout[b * 2048 + t + i * 256] = v[i] * inv;
}

// ---------------- kernel 4: context partial sums (64 s-splits for latency hiding) ----------------
__global__ __launch_bounds__(256) void ctx_partial_kernel(const float* __restrict__ enc,
                                                          const float* __restrict__ wts,
                                                          float* __restrict__ part) {
    const int b  = blockIdx.x >> 6;
    const int sp = blockIdx.x & 63;
    const int t  = threadIdx.x;
    const float* wrow = wts + b * 2048 + sp * 32;
    const float* erow = enc + ((size_t)b * 2048 + sp * 32) * 1024 + t * 4;
    float4 acc = {0.f, 0.f, 0.f, 0.f};
#pragma unroll 8
    for (int s = 0; s < 32; ++s) {
        const float w = wrow[s];
        float4 e = *reinterpret_cast<const float4*>(erow + (size_t)s * 1024);
        acc.x += w * e.x; acc.y += w * e.y; acc.z += w * e.z; acc.w += w * e.w;
    }
    *reinterpret_cast<float4*>(&part[(size_t)blockIdx.x * 1024 + t * 4]) = acc;
}

// ---------------- kernel 5: reduce partials into context ----------------
__global__ __launch_bounds__(256) void ctx_reduce_kernel(const float* __restrict__ part,
                                                         float* __restrict__ ctx) {
    const int idx = blockIdx.x * 256 + threadIdx.x;   // 0..32767
    const int b = idx >> 10, e = idx & 1023;
    float s = 0.f;
#pragma unroll
    for (int sp = 0; sp < 64; ++sp) s += part[(size_t)(b * 64 + sp) * 1024 + e];
    ctx[idx] = s;
}

extern "C" void kernel_launch(void* const* d_in, const int* in_sizes, int n_in,
                              void* d_out, int out_size, void* d_ws, size_t ws_size,
                              hipStream_t stream) {
    const float* hidden = (const float*)d_in[0];
    const float* enc    = (const float*)d_in[1];
    const int*   mask   = (const int*)d_in[2];
    const float* attn_w = (const float*)d_in[3];
    const float* attn_b = (const float*)d_in[4];
    const float* v_w    = (const float*)d_in[5];

    float* out = (float*)d_out;
    float* ctx = out;                 // 32*1024
    float* wts = out + 32 * 1024;     // 32*2048

    // workspace layout (bytes): encbf 134217728 | wbf 2097152 | hb 131072 | logits 262144 | part 8388608
    char* ws = (char*)d_ws;
    __hip_bfloat16* encbf = (__hip_bfloat16*)ws;
    __hip_bfloat16* wbf   = (__hip_bfloat16*)(ws + 134217728);
    float* hb     = (float*)(ws + 134217728 + 2097152);
    float* logits = hb + 32 * 1024;
    float* part   = logits + 32 * 2048;

    hipMemsetAsync(logits, 0, 32 * 2048 * sizeof(float), stream);
    cvt_enc_kernel<<<4096, 256, 0, stream>>>(enc, (unsigned int*)encbf);
    cvt_w_kernel<<<512, 256, 0, stream>>>(attn_w, (unsigned int*)wbf);
    hproj_kernel<<<1024, 256, 0, stream>>>(hidden, attn_w, attn_b, hb);
    energy_gemm_kernel<<<4096, 256, 0, stream>>>(encbf, wbf, hb, v_w, logits);
    softmax_kernel<<<32, 256, 0, stream>>>(logits, mask, wts);
    ctx_partial_kernel<<<2048, 256, 0, stream>>>(enc, wts, part);
    ctx_reduce_kernel<<<128, 256, 0, stream>>>(part, ctx);
}

// Round 3
// 605.496 us; speedup vs baseline: 1.1521x; 1.1014x over previous
//
#include <hip/hip_runtime.h>
#include <hip/hip_bf16.h>

#define NEG_ (-1e10f)

typedef short bf16x8 __attribute__((ext_vector_type(8)));   // 8 bf16 in 4 VGPRs
typedef float f32x4 __attribute__((ext_vector_type(4)));

__device__ __forceinline__ unsigned int pack_bf16x2(float a, float b) {
    __hip_bfloat162 h = __float22bfloat162_rn(make_float2(a, b));
    union { __hip_bfloat162 h2; unsigned int u; } cv;
    cv.h2 = h;
    return cv.u;
}

__device__ __forceinline__ float b2f(short s) {
    union { float f; unsigned u; } c;
    c.u = ((unsigned)(unsigned short)s) << 16;
    return c.f;
}

__device__ __forceinline__ void gload_lds16(const void* g, void* lds) {
    __builtin_amdgcn_global_load_lds(
        (const __attribute__((address_space(1))) unsigned int*)g,
        (__attribute__((address_space(3))) unsigned int*)lds,
        16, 0, 0);
}

// ---------------- kernel 0a: convert enc f32 -> bf16 (67.1M elems) ----------------
__global__ __launch_bounds__(256) void cvt_enc_kernel(const float* __restrict__ enc,
                                                      unsigned int* __restrict__ encbf) {
    const int tid = blockIdx.x * 256 + threadIdx.x;   // 0..1048575
#pragma unroll
    for (int i = 0; i < 8; ++i) {
        const size_t c = (size_t)tid + (size_t)i * 1048576;   // chunk of 8 floats
        const float4 a0 = *reinterpret_cast<const float4*>(enc + c * 8);
        const float4 a1 = *reinterpret_cast<const float4*>(enc + c * 8 + 4);
        uint4 u = {pack_bf16x2(a0.x, a0.y), pack_bf16x2(a0.z, a0.w),
                   pack_bf16x2(a1.x, a1.y), pack_bf16x2(a1.z, a1.w)};
        *reinterpret_cast<uint4*>(encbf + c * 4) = u;
    }
}

// ---------------- kernel 1: fused w-prep: hb[b][k] = hidden[b,:].w_h[k,:] + b[k]; wbf = bf16(w_e) ----------------
__global__ __launch_bounds__(256) void wprep_kernel(const float* __restrict__ hidden,
                                                    const float* __restrict__ attn_w,
                                                    const float* __restrict__ attn_b,
                                                    float* __restrict__ hb,
                                                    unsigned int* __restrict__ wbf) {
    __shared__ float row[2048];
    const int k = blockIdx.x;          // 0..1023
    const int t = threadIdx.x;
    // stage full attn_w row k (8 KiB)
    *reinterpret_cast<float4*>(&row[t * 8]) =
        *reinterpret_cast<const float4*>(&attn_w[(size_t)k * 2048 + t * 8]);
    *reinterpret_cast<float4*>(&row[t * 8 + 4]) =
        *reinterpret_cast<const float4*>(&attn_w[(size_t)k * 2048 + t * 8 + 4]);
    __syncthreads();
    // convert w_e half (cols 1024..2047) to bf16: 4 elems/thread
    {
        const float* s = &row[1024 + t * 4];
        uint2 u = {pack_bf16x2(s[0], s[1]), pack_bf16x2(s[2], s[3])};
        *reinterpret_cast<uint2*>(wbf + (size_t)k * 512 + t * 2) = u;
    }
    // hproj on w_h half
    const int w = t >> 6, l = t & 63;
    const float bias = attn_b[k];
    for (int bi = 0; bi < 8; ++bi) {
        const int b = w * 8 + bi;
        const float* hrow = hidden + b * 1024;
        float p = 0.f;
#pragma unroll
        for (int i = 0; i < 16; ++i) p += hrow[l + 64 * i] * row[l + 64 * i];
#pragma unroll
        for (int off = 32; off > 0; off >>= 1) p += __shfl_xor(p, off);
        if (l == 0) hb[b * 1024 + k] = p + bias;
    }
}

// ---------------- kernel 2: bf16 energy GEMM (m97 structure + T2 involution swizzle) ----------------
// logits[m] += sum_n v_w[n] * tanh( A[m,:] . B[n,:] + hb[b(m),n] ),  A=encbf, B=wbf
// M=65536, N=1024, K=1024. BM=BN=128, BK=64, 4 waves (2x2), mfma 16x16x32 bf16.
// LDS holds swizzled content: LDS(row, chunk c) = global(row, c ^ (row&7)), 16B chunks.
__global__ __launch_bounds__(256, 4) void energy_gemm_kernel(const __hip_bfloat16* __restrict__ Abf,
                                                             const __hip_bfloat16* __restrict__ Bbf,
                                                             const float* __restrict__ hb,
                                                             const float* __restrict__ v_w,
                                                             float* __restrict__ logits) {
    __shared__ short As[128 * 64];   // linear [row][64] bf16, 128 B/row
    __shared__ short Bs[128 * 64];

    const int t    = threadIdx.x;
    const int lane = t & 63;
    const int w    = t >> 6;
    const int wm   = w >> 1, wn = w & 1;

    // XCD-chunked swizzle (4096 % 8 == 0 -> bijective), ni fastest within chunk
    const int logical = (blockIdx.x & 7) * 512 + (blockIdx.x >> 3);
    const int mi = logical >> 3, ni = logical & 7;
    const size_t m0 = (size_t)mi * 128;
    const int n0 = ni * 128;
    const int b  = mi >> 4;

    f32x4 acc[4][4];
#pragma unroll
    for (int i = 0; i < 4; ++i)
#pragma unroll
        for (int j = 0; j < 4; ++j) acc[i][j] = f32x4{0.f, 0.f, 0.f, 0.f};

    // staging: wave w rows [w*32 + i*8 + (lane>>3)], row&7 == lane>>3.
    // source chunk pre-swizzled so linear LDS write lands swizzled content.
    const int csrc = (((lane & 7) ^ (lane >> 3)) * 16);
    const char* Asrc = (const char*)Abf + (m0 + w * 32 + (lane >> 3)) * 2048 + csrc;
    const char* Bsrc = (const char*)Bbf + ((size_t)n0 + w * 32 + (lane >> 3)) * 2048 + csrc;
    char* AsBase = (char*)As + w * 4096;
    char* BsBase = (char*)Bs + w * 4096;

    const int swz = lane & 7;          // fragment rows: row&7 == lane&7

    for (int kt = 0; kt < 16; ++kt) {
        const size_t ko = (size_t)kt * 128;   // byte offset along K
        __syncthreads();
#pragma unroll
        for (int i = 0; i < 4; ++i) {
            gload_lds16(Asrc + (size_t)i * 8 * 2048 + ko, AsBase + i * 1024);
            gload_lds16(Bsrc + (size_t)i * 8 * 2048 + ko, BsBase + i * 1024);
        }
        __syncthreads();
#pragma unroll
        for (int ks = 0; ks < 2; ++ks) {
            bf16x8 af[4], bfr[4];
            const int cb = ((ks * 4 + (lane >> 4)) ^ swz) * 16;   // un-swizzle on read
#pragma unroll
            for (int fm = 0; fm < 4; ++fm)
                af[fm] = *reinterpret_cast<const bf16x8*>(
                    (const char*)As + (wm * 64 + fm * 16 + (lane & 15)) * 128 + cb);
#pragma unroll
            for (int fn = 0; fn < 4; ++fn)
                bfr[fn] = *reinterpret_cast<const bf16x8*>(
                    (const char*)Bs + (wn * 64 + fn * 16 + (lane & 15)) * 128 + cb);
#pragma unroll
            for (int fm = 0; fm < 4; ++fm)
#pragma unroll
                for (int fn = 0; fn < 4; ++fn)
                    acc[fm][fn] = __builtin_amdgcn_mfma_f32_16x16x32_bf16(
                        af[fm], bfr[fn], acc[fm][fn], 0, 0, 0);
        }
    }

    // epilogue: tanh + v_w weighting + row reduction (validated R1/R2)
    const int cl = lane & 15, rg = lane >> 4;
    float rs[4][4];
#pragma unroll
    for (int i = 0; i < 4; ++i)
#pragma unroll
        for (int j = 0; j < 4; ++j) rs[i][j] = 0.f;

#pragma unroll
    for (int fn = 0; fn < 4; ++fn) {
        const int n = n0 + wn * 64 + fn * 16 + cl;
        const float hbv = hb[b * 1024 + n];
        const float vwv = v_w[n];
#pragma unroll
        for (int fm = 0; fm < 4; ++fm) {
#pragma unroll
            for (int r = 0; r < 4; ++r) {
                float x  = acc[fm][fn][r] + hbv;
                float x2 = fminf(fmaxf(2.f * x, -80.f), 80.f);
                float ex = __expf(x2);
                float th = 1.f - 2.f / (ex + 1.f);
                rs[fm][r] += th * vwv;
            }
        }
    }
#pragma unroll
    for (int fm = 0; fm < 4; ++fm) {
#pragma unroll
        for (int r = 0; r < 4; ++r) {
            float v = rs[fm][r];
            v += __shfl_xor(v, 1);
            v += __shfl_xor(v, 2);
            v += __shfl_xor(v, 4);
            v += __shfl_xor(v, 8);
            if (cl == 0)
                atomicAdd(&logits[m0 + wm * 64 + fm * 16 + rg * 4 + r], v);
        }
    }
}

// ---------------- kernel 3: masked softmax over S=2048 per batch row ----------------
__global__ __launch_bounds__(256) void softmax_kernel(const float* __restrict__ logits,
                                                      const int* __restrict__ mask,
                                                      float* __restrict__ wout) {
    const int b = blockIdx.x, t = threadIdx.x;
    __shared__ float red[4];
    float v[8];
    float m = -3.4e38f;
#pragma unroll
    for (int i = 0; i < 8; ++i) {
        const int s = t + i * 256;
        float x = logits[b * 2048 + s];
        if (mask[b * 2048 + s] == 0) x = NEG_;
        v[i] = x;
        m = fmaxf(m, x);
    }
#pragma unroll
    for (int off = 32; off > 0; off >>= 1) m = fmaxf(m, __shfl_xor(m, off));
    if ((t & 63) == 0) red[t >> 6] = m;
    __syncthreads();
    m = fmaxf(fmaxf(red[0], red[1]), fmaxf(red[2], red[3]));
    __syncthreads();
    float sum = 0.f;
#pragma unroll
    for (int i = 0; i < 8; ++i) {
        v[i] = __expf(v[i] - m);
        sum += v[i];
    }
#pragma unroll
    for (int off = 32; off > 0; off >>= 1) sum += __shfl_xor(sum, off);
    if ((t & 63) == 0) red[t >> 6] = sum;
    __syncthreads();
    sum = red[0] + red[1] + red[2] + red[3];
    const float inv = 1.f / sum;
#pragma unroll
    for (int i = 0; i < 8; ++i) wout[b * 2048 + t + i * 256] = v[i] * inv;
}

// ---------------- kernel 4: context partials (bf16 enc) + atomic reduce into ctx ----------------
__global__ __launch_bounds__(256) void ctx_partial_kernel(const __hip_bfloat16* __restrict__ encbf,
                                                          const float* __restrict__ wts,
                                                          float* __restrict__ ctx) {
    const int b  = blockIdx.x >> 6;
    const int sp = blockIdx.x & 63;
    const int t  = threadIdx.x;
    const float* wrow = wts + b * 2048 + sp * 32;
    const char* base = (const char*)encbf + ((size_t)b * 2048 + sp * 32) * 2048 + t * 8;
    float4 acc = {0.f, 0.f, 0.f, 0.f};
#pragma unroll 8
    for (int s = 0; s < 32; ++s) {
        const float wv = wrow[s];
        short4 e = *reinterpret_cast<const short4*>(base + (size_t)s * 2048);
        acc.x += wv * b2f(e.x); acc.y += wv * b2f(e.y);
        acc.z += wv * b2f(e.z); acc.w += wv * b2f(e.w);
    }
    float* dst = ctx + b * 1024 + t * 4;
    atomicAdd(dst + 0, acc.x);
    atomicAdd(dst + 1, acc.y);
    atomicAdd(dst + 2, acc.z);
    atomicAdd(dst + 3, acc.w);
}

extern "C" void kernel_launch(void* const* d_in, const int* in_sizes, int n_in,
                              void* d_out, int out_size, void* d_ws, size_t ws_size,
                              hipStream_t stream) {
    const float* hidden = (const float*)d_in[0];
    const float* enc    = (const float*)d_in[1];
    const int*   mask   = (const int*)d_in[2];
    const float* attn_w = (const float*)d_in[3];
    const float* attn_b = (const float*)d_in[4];
    const float* v_w    = (const float*)d_in[5];

    float* out = (float*)d_out;
    float* ctx = out;                 // 32*1024
    float* wts = out + 32 * 1024;     // 32*2048

    // workspace layout (bytes): encbf 134217728 | wbf 2097152 | hb 131072 | logits 262144
    char* ws = (char*)d_ws;
    __hip_bfloat16* encbf = (__hip_bfloat16*)ws;
    __hip_bfloat16* wbf   = (__hip_bfloat16*)(ws + 134217728);
    float* hb     = (float*)(ws + 134217728 + 2097152);
    float* logits = hb + 32 * 1024;

    hipMemsetAsync(logits, 0, 32 * 2048 * sizeof(float), stream);
    hipMemsetAsync(ctx, 0, 32 * 1024 * sizeof(float), stream);
    cvt_enc_kernel<<<4096, 256, 0, stream>>>(enc, (unsigned int*)encbf);
    wprep_kernel<<<1024, 256, 0, stream>>>(hidden, attn_w, attn_b, hb, (unsigned int*)wbf);
    energy_gemm_kernel<<<4096, 256, 0, stream>>>(encbf, wbf, hb, v_w, logits);
    softmax_kernel<<<32, 256, 0, stream>>>(logits, mask, wts);
    ctx_partial_kernel<<<2048, 256, 0, stream>>>(encbf, wts, ctx);
}